// Round 7
// baseline (289.520 us; speedup 1.0000x reference)
//
#include <hip/hip_runtime.h>
#include <math.h>

#define B_   8
#define T_   2048
#define NE_  384
#define HQ_  8
#define HKV_ 2
#define D_   48
#define DH_  24   // D/2

typedef __attribute__((ext_vector_type(8))) short bf16x8;
typedef __attribute__((ext_vector_type(4))) short bf16x4;
typedef __attribute__((ext_vector_type(4))) float f32x4;

static __device__ __forceinline__ short f2bf(float f) {
    union { float f; unsigned u; } v; v.f = f;
    unsigned r = (v.u + 0x7fffu + ((v.u >> 16) & 1u)) >> 16;
    return (short)r;
}

// ---------------- kernel 0: prep (convert + transpose + rope table) --------
__global__ __launch_bounds__(256) void prep_kernel(
    const float* __restrict__ x, const float* __restrict__ wq,
    const float* __restrict__ wk, const float* __restrict__ wv,
    const float* __restrict__ wo,
    short* __restrict__ xb, short* __restrict__ wt, short* __restrict__ wot,
    float* __restrict__ ct, float* __restrict__ st)
{
    const int bid = blockIdx.x, tid = threadIdx.x;
    if (bid < 6144) {
        int i = bid * 256 + tid;                 // float4 index, 1572864 total
        float4 v = ((const float4*)x)[i];
        bf16x4 o = { f2bf(v.x), f2bf(v.y), f2bf(v.z), f2bf(v.w) };
        *(bf16x4*)&xb[(size_t)i * 4] = o;
    } else if (bid < 7008) {
        int e = (bid - 6144) * 256 + tid;        // < 221184
        int n = e / 384, k = e - n * 384;
        float s = (n < 384) ? wq[(size_t)k * 384 + n]
                : (n < 480) ? wk[(size_t)k * 96 + (n - 384)]
                            : wv[(size_t)k * 96 + (n - 480)];
        wt[e] = f2bf(s);
    } else if (bid < 7584) {
        int e = (bid - 7008) * 256 + tid;        // < 147456
        int n = e / 384, k = e - n * 384;
        wot[e] = f2bf(wo[(size_t)k * 384 + n]);
    } else {
        int i = (bid - 7584) * 256 + tid;        // < 49152
        int t = i / DH_, j = i - t * DH_;
        double inv = pow(10000.0, -(double)(2 * j) / (double)D_);
        double ang = (double)t * inv;
        ct[i] = (float)cos(ang);
        st[i] = (float)sin(ang);
    }
}

// ---------------- kernel 1: QKV MFMA GEMM + fused RoPE (R6-identical) ------
#define GP 40   // LDS pitch in shorts: 80B rows -> 2-way banking (free)
__global__ __launch_bounds__(256) void qkv_gemm_kernel(
    const short* __restrict__ xb, const short* __restrict__ wt,
    const float* __restrict__ ct, const float* __restrict__ st,
    short* __restrict__ qb, short* __restrict__ kb, short* __restrict__ vtb)
{
    const int tid = threadIdx.x;
    const int n0 = blockIdx.x * 64;     // 9 tiles
    const int m0 = blockIdx.y * 128;    // 128 tiles
    __shared__ short As[128 * GP];
    __shared__ short Bs[64 * GP];
    const int lane = tid & 63, w = tid >> 6;
    const int c = lane & 15, u = lane >> 4;
    const int mo = (w & 1) * 64, no = (w >> 1) * 32;
    f32x4 acc[4][2] = {};

    for (int kt = 0; kt < 384; kt += 32) {
        __syncthreads();
#pragma unroll
        for (int p = 0; p < 2; ++p) {
            int f = tid + p * 256;
            int row = f >> 2, j = f & 3;
            bf16x8 v = *(const bf16x8*)&xb[(size_t)(m0 + row) * 384 + kt + j * 8];
            *(bf16x8*)&As[row * GP + j * 8] = v;
        }
        {
            int row = tid >> 2, j = tid & 3;
            bf16x8 v = *(const bf16x8*)&wt[(size_t)(n0 + row) * 384 + kt + j * 8];
            *(bf16x8*)&Bs[row * GP + j * 8] = v;
        }
        __syncthreads();
        bf16x8 af[4], bfr[2];
#pragma unroll
        for (int i = 0; i < 4; ++i) af[i] = *(bf16x8*)&As[(mo + 16 * i + c) * GP + 8 * u];
#pragma unroll
        for (int j = 0; j < 2; ++j) bfr[j] = *(bf16x8*)&Bs[(no + 16 * j + c) * GP + 8 * u];
#pragma unroll
        for (int i = 0; i < 4; ++i)
#pragma unroll
            for (int j = 0; j < 2; ++j)
                acc[i][j] = __builtin_amdgcn_mfma_f32_16x16x32_bf16(af[i], bfr[j], acc[i][j], 0, 0, 0);
    }

    const float qscale = 0.14433756729740643f;  // 1/sqrt(48)
#pragma unroll
    for (int i = 0; i < 4; ++i) {
#pragma unroll
        for (int j = 0; j < 2; ++j) {
            int n = n0 + no + 16 * j + c;        // region uniform per 16-wide subtile
            int mb = m0 + mo + 16 * i + 4 * u;
            int b = mb >> 11;
            int t0 = mb & 2047;
            if (n < 480) {                       // q or k: RoPE, 64-padded store
                int nn = (n < 384) ? n : n - 384;
                int h = nn / 48, d = nn - h * 48;
                int fi = d >> 1;
                float sgn = (d & 1) ? 1.0f : -1.0f;
                float scl = (n < 384) ? qscale : 1.0f;
                short* dst = (n < 384) ? qb : kb;
                size_t base = (n < 384)
                    ? ((size_t)(b * HQ_ + h) * T_ + t0) * 64 + d
                    : ((size_t)(b * HKV_ + h) * T_ + t0) * 64 + d;
#pragma unroll
                for (int r = 0; r < 4; ++r) {
                    float val = acc[i][j][r];
                    float part = __shfl_xor(val, 1);
                    float cs = ct[(t0 + r) * DH_ + fi], sn = st[(t0 + r) * DH_ + fi];
                    dst[base + (size_t)r * 64] = f2bf((val * cs + sgn * part * sn) * scl);
                }
            } else {                             // v: no rope, transposed store
                int nn = n - 480;
                int h = nn / 48, d = nn - h * 48;
                ushort4 pk;
                pk.x = (unsigned short)f2bf(acc[i][j][0]);
                pk.y = (unsigned short)f2bf(acc[i][j][1]);
                pk.z = (unsigned short)f2bf(acc[i][j][2]);
                pk.w = (unsigned short)f2bf(acc[i][j][3]);
                *(ushort4*)&vtb[((size_t)(b * HKV_ + h) * D_ + d) * T_ + t0] = pk;
            }
        }
    }
}

// ---------------- kernel 2: LDS-free head-fused MFMA flash attention -------
// R6-verified math + register double-buffer prefetch of next K/V tile.
struct KV {
    bf16x8 klo[4];      // K[16mt+c][d 0..31]
    bf16x8 khi[4];      // K[16mt+c][d 32..63] (pad zeroed)
    bf16x4 vf[3][4];    // Vt[d=16nt+c][k 16kt+4u..]
};

__device__ __forceinline__ void kv_load(KV& F, const short* kjt, const short* vjt) {
#pragma unroll
    for (int mt = 0; mt < 4; ++mt) {
        F.klo[mt] = *(const bf16x8*)(kjt + mt * 1024);
        F.khi[mt] = *(const bf16x8*)(kjt + mt * 1024 + 32);
    }
#pragma unroll
    for (int nt = 0; nt < 3; ++nt)
#pragma unroll
        for (int k2 = 0; k2 < 4; ++k2)
            F.vf[nt][k2] = *(const bf16x4*)(vjt + nt * 16 * T_ + k2 * 16);
}

__device__ __forceinline__ void kv_step(const KV& F, const bf16x8 (&qf0)[2],
                                        const bf16x8 (&qf1)[2],
                                        f32x4 (&o)[2][3], float (&m_s)[2],
                                        float (&l_s)[2], bool diag,
                                        int w, int u, int c)
{
    const int mtmax = diag ? (w + 1) : 4;
#pragma unroll
    for (int g = 0; g < 2; ++g) {
        // S^T tiles: s[mt] = S^T[k=16mt+4u+r][q=16w+c]
        f32x4 s[4];
#pragma unroll
        for (int mt = 0; mt < 4; ++mt) {
            if (mt < mtmax) {
                f32x4 a = {0.f, 0.f, 0.f, 0.f};
                a = __builtin_amdgcn_mfma_f32_16x16x32_bf16(F.klo[mt], qf0[g], a, 0, 0, 0);
                a = __builtin_amdgcn_mfma_f32_16x16x32_bf16(F.khi[mt], qf1[g], a, 0, 0, 0);
                if (diag && mt == mtmax - 1) {      // diagonal 16x16 tile
#pragma unroll
                    for (int r = 0; r < 4; ++r)
                        a[r] = (4 * u + r > c) ? -1e30f : a[r];
                }
                s[mt] = a;
            }
        }

        float mloc = -1e30f;
#pragma unroll
        for (int mt = 0; mt < 4; ++mt)
            if (mt < mtmax)
                mloc = fmaxf(mloc, fmaxf(fmaxf(s[mt][0], s[mt][1]),
                                         fmaxf(s[mt][2], s[mt][3])));
        mloc = fmaxf(mloc, __shfl_xor(mloc, 16));
        mloc = fmaxf(mloc, __shfl_xor(mloc, 32));
        float mnew = fmaxf(m_s[g], mloc);
        float alpha = __expf(m_s[g] - mnew);
        m_s[g] = mnew;
        float psum = 0.0f;
        bf16x4 pf[4];
#pragma unroll
        for (int mt = 0; mt < 4; ++mt) {
            if (mt < mtmax) {
                float p0 = __expf(s[mt][0] - mnew);
                float p1 = __expf(s[mt][1] - mnew);
                float p2 = __expf(s[mt][2] - mnew);
                float p3 = __expf(s[mt][3] - mnew);
                psum += (p0 + p1) + (p2 + p3);
                pf[mt] = { f2bf(p0), f2bf(p1), f2bf(p2), f2bf(p3) };
            }
        }
        psum += __shfl_xor(psum, 16);
        psum += __shfl_xor(psum, 32);
        l_s[g] = l_s[g] * alpha + psum;

        float a0 = __shfl(alpha, 4 * u + 0);
        float a1 = __shfl(alpha, 4 * u + 1);
        float a2 = __shfl(alpha, 4 * u + 2);
        float a3 = __shfl(alpha, 4 * u + 3);
#pragma unroll
        for (int nt = 0; nt < 3; ++nt) {
            o[g][nt][0] *= a0; o[g][nt][1] *= a1;
            o[g][nt][2] *= a2; o[g][nt][3] *= a3;
        }
#pragma unroll
        for (int k2 = 0; k2 < 4; ++k2) {
            if (k2 < mtmax) {
#pragma unroll
                for (int nt = 0; nt < 3; ++nt)
                    o[g][nt] = __builtin_amdgcn_mfma_f32_16x16x16bf16_1k(
                        pf[k2], F.vf[nt][k2], o[g][nt], 0, 0, 0);
            }
        }
    }
}

__global__ __launch_bounds__(256, 2) void attn_kernel(
    const short* __restrict__ qb, const short* __restrict__ kb,
    const short* __restrict__ vtb, short* __restrict__ aob)
{
    const int tid = threadIdx.x;
    const int x  = blockIdx.x;          // 0..15: qt = 31-x then qt = x
    const int hk = blockIdx.y >> 1;     // 0..1
    const int gp = blockIdx.y & 1;      // head pair within group
    const int b  = blockIdx.z;
    const int lane = tid & 63;
    const int w = tid >> 6;             // q-subtile: q rows 16w..16w+15
    const int c = lane & 15;
    const int u = lane >> 4;

    const short* kbase = kb  + (size_t)(b * HKV_ + hk) * T_ * 64 + c * 64 + 8 * u;
    const short* vbase = vtb + (size_t)(b * HKV_ + hk) * D_ * T_ + c * T_ + 4 * u;

#pragma unroll 1
    for (int ph = 0; ph < 2; ++ph) {
        const int qt = ph ? x : 31 - x;     // complementary pair: 33 iters total
        bf16x8 qf0[2], qf1[2];
#pragma unroll
        for (int g = 0; g < 2; ++g) {
            int h = hk * 4 + gp * 2 + g;
            const short* qp = qb + ((size_t)(b * HQ_ + h) * T_ + qt * 64 + 16 * w + c) * 64;
            qf0[g] = *(const bf16x8*)(qp + 8 * u);          // d 0..31
            qf1[g] = *(const bf16x8*)(qp + 32 + 8 * u);     // d 32..63 (pad=0)
        }
        float m_s[2] = { -1e30f, -1e30f };
        float l_s[2] = { 0.f, 0.f };
        f32x4 o[2][3] = {};

        KV FA, FB;
        kv_load(FA, kbase, vbase);
        int jt = 0;
#pragma unroll 1
        for (;;) {
            if (jt < qt) kv_load(FB, kbase + (jt + 1) * 4096, vbase + (jt + 1) * 64);
            kv_step(FA, qf0, qf1, o, m_s, l_s, jt == qt, w, u, c);
            if (++jt > qt) break;
            if (jt < qt) kv_load(FA, kbase + (jt + 1) * 4096, vbase + (jt + 1) * 64);
            kv_step(FB, qf0, qf1, o, m_s, l_s, jt == qt, w, u, c);
            if (++jt > qt) break;
        }

        // epilogue: O rows 16w+4u+r, cols 16nt+c (per head)
#pragma unroll
        for (int g = 0; g < 2; ++g) {
            int h = hk * 4 + gp * 2 + g;
            float li = 1.0f / l_s[g];
            float l0 = __shfl(li, 4 * u + 0);
            float l1 = __shfl(li, 4 * u + 1);
            float l2 = __shfl(li, 4 * u + 2);
            float l3 = __shfl(li, 4 * u + 3);
            float lr[4] = { l0, l1, l2, l3 };
#pragma unroll
            for (int nt = 0; nt < 3; ++nt)
#pragma unroll
                for (int r = 0; r < 4; ++r) {
                    int t = qt * 64 + 16 * w + 4 * u + r;
                    aob[((size_t)b * T_ + t) * NE_ + h * D_ + 16 * nt + c] =
                        f2bf(o[g][nt][r] * lr[r]);
                }
        }
    }
}

// ---------------- kernel 3: out projection MFMA + bias ----------------
__global__ __launch_bounds__(256) void out_gemm_kernel(
    const short* __restrict__ aob, const short* __restrict__ wot,
    const float* __restrict__ bias, float* __restrict__ out)
{
    const int tid = threadIdx.x;
    const int n0 = blockIdx.x * 64;     // 6 tiles
    const int m0 = blockIdx.y * 128;    // 128 tiles
    __shared__ short As[128 * GP];
    __shared__ short Bs[64 * GP];
    const int lane = tid & 63, w = tid >> 6;
    const int c = lane & 15, u = lane >> 4;
    const int mo = (w & 1) * 64, no = (w >> 1) * 32;
    f32x4 acc[4][2] = {};

    for (int kt = 0; kt < 384; kt += 32) {
        __syncthreads();
#pragma unroll
        for (int p = 0; p < 2; ++p) {
            int f = tid + p * 256;
            int row = f >> 2, j = f & 3;
            bf16x8 v = *(const bf16x8*)&aob[(size_t)(m0 + row) * 384 + kt + j * 8];
            *(bf16x8*)&As[row * GP + j * 8] = v;
        }
        {
            int row = tid >> 2, j = tid & 3;
            bf16x8 v = *(const bf16x8*)&wot[(size_t)(n0 + row) * 384 + kt + j * 8];
            *(bf16x8*)&Bs[row * GP + j * 8] = v;
        }
        __syncthreads();
        bf16x8 af[4], bfr[2];
#pragma unroll
        for (int i = 0; i < 4; ++i) af[i] = *(bf16x8*)&As[(mo + 16 * i + c) * GP + 8 * u];
#pragma unroll
        for (int j = 0; j < 2; ++j) bfr[j] = *(bf16x8*)&Bs[(no + 16 * j + c) * GP + 8 * u];
#pragma unroll
        for (int i = 0; i < 4; ++i)
#pragma unroll
            for (int j = 0; j < 2; ++j)
                acc[i][j] = __builtin_amdgcn_mfma_f32_16x16x32_bf16(af[i], bfr[j], acc[i][j], 0, 0, 0);
    }

#pragma unroll
    for (int i = 0; i < 4; ++i) {
#pragma unroll
        for (int j = 0; j < 2; ++j) {
            int n = n0 + no + 16 * j + c;
            int mb = m0 + mo + 16 * i + 4 * u;
            float bv = bias[n];
#pragma unroll
            for (int r = 0; r < 4; ++r)
                out[(size_t)(mb + r) * 384 + n] = acc[i][j][r] + bv;
        }
    }
}

// ---------------- launcher ----------------
extern "C" void kernel_launch(void* const* d_in, const int* in_sizes, int n_in,
                              void* d_out, int out_size, void* d_ws, size_t ws_size,
                              hipStream_t stream) {
    const float* x  = (const float*)d_in[0];
    const float* wq = (const float*)d_in[1];
    const float* wk = (const float*)d_in[2];
    const float* wv = (const float*)d_in[3];
    const float* wo = (const float*)d_in[4];
    const float* bo = (const float*)d_in[5];
    float* out = (float*)d_out;

    float* ct  = (float*)d_ws;                       // 49152 f32
    float* st  = ct + 49152;                         // 49152 f32
    short* xb  = (short*)(st + 49152);               // 16384*384
    short* wt  = xb  + (size_t)16384 * 384;          // 576*384
    short* wot = wt  + (size_t)576 * 384;            // 384*384
    short* qb  = wot + (size_t)384 * 384;            // 8*8*2048*64 (d-padded)
    short* kb  = qb  + (size_t)B_ * HQ_  * T_ * 64;  // 8*2*2048*64 (d-padded)
    short* vtb = kb  + (size_t)B_ * HKV_ * T_ * 64;  // 8*2*48*2048 (transposed)
    short* aob = vtb + (size_t)B_ * HKV_ * D_ * T_;  // 16384*384
    // total ~50.4 MB

    hipLaunchKernelGGL(prep_kernel, dim3(7776), dim3(256), 0, stream,
                       x, wq, wk, wv, wo, xb, wt, wot, ct, st);
    // zero qb+kb (adjacent) so d-pad cols 48..63 are 0 for the MFMA K-dim
    hipMemsetAsync(qb, 0, ((size_t)B_ * HQ_ * T_ * 64 + (size_t)B_ * HKV_ * T_ * 64) * sizeof(short), stream);
    hipLaunchKernelGGL(qkv_gemm_kernel, dim3(9, 128), dim3(256), 0, stream,
                       xb, wt, ct, st, qb, kb, vtb);
    hipLaunchKernelGGL(attn_kernel, dim3(16, 4, 8), dim3(256), 0, stream,
                       qb, kb, vtb, aob);
    hipLaunchKernelGGL(out_gemm_kernel, dim3(6, 128), dim3(256), 0, stream,
                       aob, wot, bo, out);
}